// Round 16
// baseline (767.398 us; speedup 1.0000x reference)
//
#include <hip/hip_runtime.h>
#include <cstdint>

// ---- problem constants ----
#define H_    2048
#define NQ_   16
#define NKV_  4
#define HD_   128
#define FF_   8192
#define B_    2
#define S_    2048
#define TOK   (B_*S_)            // 4096 tokens
#define QKVN  (H_ + 2*NKV_*HD_)  // 3072 = Q(2048) | K(512) | V(512)
#define KVB   64                 // attention KV tile

typedef __bf16 bf16;
typedef bf16  bf16x8 __attribute__((ext_vector_type(8)));
typedef float f32x4  __attribute__((ext_vector_type(4)));

typedef __attribute__((address_space(1))) void as1_void;
typedef __attribute__((address_space(3))) void as3_void;

__device__ __forceinline__ void gload_lds16(const void* g, void* l) {
    __builtin_amdgcn_global_load_lds((as1_void*)g, (as3_void*)l, 16, 0, 0);
}

// ======================================================================
// Weight convert + transpose: W[K][N] f32 -> Wt[outOff+N][K] bf16
// ======================================================================
__global__ __launch_bounds__(256) void wtrans_kernel(
    const float* __restrict__ W, bf16* __restrict__ Wt, int K, int N, int outOff)
{
    __shared__ float tile[32][33];
    const int n0 = (int)blockIdx.x * 32;
    const int k0 = (int)blockIdx.y * 32;
    const int c  = (int)threadIdx.x & 31;
    const int r  = (int)threadIdx.x >> 5;
#pragma unroll
    for (int i = 0; i < 4; ++i)
        tile[r + i*8][c] = W[(size_t)(k0 + r + i*8) * N + n0 + c];
    __syncthreads();
#pragma unroll
    for (int i = 0; i < 4; ++i)
        Wt[(size_t)(outOff + n0 + r + i*8) * K + k0 + c] = (bf16)tile[c][r + i*8];
}

__global__ void biaspack_kernel(const float* __restrict__ bq, const float* __restrict__ bk,
                                const float* __restrict__ bv, float* __restrict__ out)
{
    const int i = (int)(blockIdx.x * 256 + threadIdx.x);
    out[i] = (i < H_) ? bq[i] : (i < H_ + NKV_*HD_ ? bk[i - H_] : bv[i - H_ - NKV_*HD_]);
}

// ======================================================================
// RMSNorm: x f32 [rows][2048] -> y bf16
// ======================================================================
__global__ __launch_bounds__(256) void rmsnorm_kernel(
    const float* __restrict__ x, const float* __restrict__ g, bf16* __restrict__ y)
{
    const int row = (int)blockIdx.x;
    const int tid = (int)threadIdx.x;
    const float* xr = x + (size_t)row * H_;
    const float4 a = *(const float4*)(xr + tid*8);
    const float4 c = *(const float4*)(xr + tid*8 + 4);
    float ss = a.x*a.x + a.y*a.y + a.z*a.z + a.w*a.w
             + c.x*c.x + c.y*c.y + c.z*c.z + c.w*c.w;
#pragma unroll
    for (int d = 1; d < 64; d <<= 1) ss += __shfl_xor(ss, d);
    __shared__ float red[4];
    if ((tid & 63) == 0) red[tid >> 6] = ss;
    __syncthreads();
    const float inv = rsqrtf((red[0]+red[1]+red[2]+red[3]) * (1.0f/H_) + 1e-6f);
    const float vals[8] = {a.x,a.y,a.z,a.w,c.x,c.y,c.z,c.w};
    const float* gp = g + tid*8;
    bf16x8 outv;
#pragma unroll
    for (int e = 0; e < 8; ++e) outv[e] = (bf16)(vals[e] * inv * gp[e]);
    *(bf16x8*)(y + (size_t)row * H_ + tid*8) = outv;
}

// ======================================================================
// V transpose: qkv[tok][3072] V-slice -> Vt[(b*NKV+kh)*HD + d][S]
// ======================================================================
__global__ __launch_bounds__(256) void vtrans_kernel(
    const bf16* __restrict__ qkv, bf16* __restrict__ Vt)
{
    __shared__ bf16 tile[32][33];
    const int tt = (int)blockIdx.x;
    const int d0 = (int)blockIdx.y * 32;
    const int kh = (int)blockIdx.z;
    const int b  = (tt*32) / S_;
    const int s0 = (tt*32) % S_;
    const int c = (int)threadIdx.x & 31;
    const int r = (int)threadIdx.x >> 5;
#pragma unroll
    for (int i = 0; i < 4; ++i)
        tile[r + i*8][c] = qkv[(size_t)(tt*32 + r + i*8)*QKVN + H_ + NKV_*HD_ + kh*HD_ + d0 + c];
    __syncthreads();
#pragma unroll
    for (int i = 0; i < 4; ++i)
        Vt[((size_t)(b*NKV_ + kh)*HD_ + d0 + r + i*8)*S_ + s0 + c] = tile[c][r + i*8];
}

// ======================================================================
// GEMM (r11/r15 exact, swizzled): best measured. QKV / O-proj / FFN2
// (in-round controls for the FFN1 no-swizzle experiment).
// MODE 0: +bias -> bf16. 1: GELU(v+bias) -> bf16. 2: v+bias+resid -> f32.
// ======================================================================
template<int MODE>
__global__ __launch_bounds__(256, 3) void gemm_kernel(
    const bf16* __restrict__ A, const bf16* __restrict__ Bt,
    const float* __restrict__ bias, const float* __restrict__ resid,
    void* __restrict__ Cout, int M, int N, int K)
{
    __shared__ bf16 lA[128*64];
    __shared__ bf16 lB[128*64];
    const int tid  = (int)threadIdx.x;
    const int wid  = tid >> 6;
    const int lane = tid & 63;
    const int lr   = lane & 15;
    const int lg   = lane >> 4;

    const int gx  = (int)gridDim.x;
    const int nwg = gx * (int)gridDim.y;
    int wg = (int)blockIdx.y * gx + (int)blockIdx.x;
    wg = (wg & 7) * (nwg >> 3) + (wg >> 3);
    const int nsup  = gx >> 2;
    const int chunk = wg >> 5;
    const int cin   = wg & 31;
    const int m0 = ((chunk / nsup) * 8 + (cin >> 2)) * 128;
    const int n0 = ((chunk % nsup) * 4 + (cin & 3)) * 128;

    const int wm = (wid >> 1) * 64;
    const int wn = (wid & 1) * 64;

    f32x4 acc[4][4] = {};

    const int sRow = wid*32 + (lane >> 3);
    const int sCol = ((lane & 7) ^ (lane >> 3)) * 8;
    const bf16* aSrc = A  + (size_t)(m0 + sRow) * K + sCol;
    const bf16* bSrc = Bt + (size_t)(n0 + sRow) * K + sCol;

    for (int k0 = 0; k0 < K; k0 += 64) {
#pragma unroll
        for (int i = 0; i < 4; ++i) {
            gload_lds16(aSrc + (size_t)(i*8)*K + k0, &lA[(wid*32 + i*8)*64]);
            gload_lds16(bSrc + (size_t)(i*8)*K + k0, &lB[(wid*32 + i*8)*64]);
        }
        __syncthreads();
#pragma unroll
        for (int kk = 0; kk < 64; kk += 32) {
            const int ks = (kk + lg*8) ^ ((lr & 7) * 8);
            bf16x8 af[4], bfr[4];
#pragma unroll
            for (int i = 0; i < 4; ++i)
                af[i] = *(const bf16x8*)&lA[(wm + i*16 + lr)*64 + ks];
#pragma unroll
            for (int j = 0; j < 4; ++j)
                bfr[j] = *(const bf16x8*)&lB[(wn + j*16 + lr)*64 + ks];
#pragma unroll
            for (int i = 0; i < 4; ++i)
#pragma unroll
                for (int j = 0; j < 4; ++j)
                    acc[i][j] = __builtin_amdgcn_mfma_f32_16x16x32_bf16(
                        af[i], bfr[j], acc[i][j], 0, 0, 0);
        }
        __syncthreads();
    }

#pragma unroll
    for (int j = 0; j < 4; ++j) {
        const int col = n0 + wn + j*16 + lr;
        const float bj = bias[col];
#pragma unroll
        for (int i = 0; i < 4; ++i) {
            const int row0 = m0 + wm + i*16 + lg*4;
#pragma unroll
            for (int rr = 0; rr < 4; ++rr) {
                float v = acc[i][j][rr] + bj;
                const size_t idx = (size_t)(row0 + rr) * N + col;
                if (MODE == 2) {
                    ((float*)Cout)[idx] = v + resid[idx];
                } else {
                    if (MODE == 1) v = 0.5f * v * (1.0f + erff(v * 0.70710678118654752f));
                    ((bf16*)Cout)[idx] = (bf16)v;
                }
            }
        }
    }
}

// ======================================================================
// GEMM no-swizzle EXPERIMENT (FFN1 only) — the single never-tested
// variable vs m97's 874 TF reference: LINEAR LDS (linear staging
// source, linear fragment reads, no XOR anywhere). Every kernel since
// round 0 carried the XOR swizzle; m97's measurement did not. Possible
// hurt mechanisms of the swizzle: XOR address dependency in the
// fragment-read path, and permuted (non-affine) source addresses
// defeating VMEM offset folding. Everything else identical to
// gemm_kernel (superblock mapping, launch_bounds, schedule, epilogue).
// ======================================================================
template<int MODE>
__global__ __launch_bounds__(256, 3) void gemm_nosw_kernel(
    const bf16* __restrict__ A, const bf16* __restrict__ Bt,
    const float* __restrict__ bias, const float* __restrict__ resid,
    void* __restrict__ Cout, int M, int N, int K)
{
    __shared__ bf16 lA[128*64];
    __shared__ bf16 lB[128*64];
    const int tid  = (int)threadIdx.x;
    const int wid  = tid >> 6;
    const int lane = tid & 63;
    const int lr   = lane & 15;
    const int lg   = lane >> 4;

    const int gx  = (int)gridDim.x;
    const int nwg = gx * (int)gridDim.y;
    int wg = (int)blockIdx.y * gx + (int)blockIdx.x;
    wg = (wg & 7) * (nwg >> 3) + (wg >> 3);
    const int nsup  = gx >> 2;
    const int chunk = wg >> 5;
    const int cin   = wg & 31;
    const int m0 = ((chunk / nsup) * 8 + (cin >> 2)) * 128;
    const int n0 = ((chunk % nsup) * 4 + (cin & 3)) * 128;

    const int wm = (wid >> 1) * 64;
    const int wn = (wid & 1) * 64;

    f32x4 acc[4][4] = {};

    // LINEAR staging: lane l covers row (l>>3), bytes (l&7)*16 of each
    // 8-row chunk -- contiguous 1KB per instruction, no pre-XOR.
    const int sRow = wid*32 + (lane >> 3);
    const int sCol = (lane & 7) * 8;
    const bf16* aSrc = A  + (size_t)(m0 + sRow) * K + sCol;
    const bf16* bSrc = Bt + (size_t)(n0 + sRow) * K + sCol;

    for (int k0 = 0; k0 < K; k0 += 64) {
#pragma unroll
        for (int i = 0; i < 4; ++i) {
            gload_lds16(aSrc + (size_t)(i*8)*K + k0, &lA[(wid*32 + i*8)*64]);
            gload_lds16(bSrc + (size_t)(i*8)*K + k0, &lB[(wid*32 + i*8)*64]);
        }
        __syncthreads();
#pragma unroll
        for (int kk = 0; kk < 64; kk += 32) {
            const int ks = kk + lg*8;     // linear fragment read, no XOR
            bf16x8 af[4], bfr[4];
#pragma unroll
            for (int i = 0; i < 4; ++i)
                af[i] = *(const bf16x8*)&lA[(wm + i*16 + lr)*64 + ks];
#pragma unroll
            for (int j = 0; j < 4; ++j)
                bfr[j] = *(const bf16x8*)&lB[(wn + j*16 + lr)*64 + ks];
#pragma unroll
            for (int i = 0; i < 4; ++i)
#pragma unroll
                for (int j = 0; j < 4; ++j)
                    acc[i][j] = __builtin_amdgcn_mfma_f32_16x16x32_bf16(
                        af[i], bfr[j], acc[i][j], 0, 0, 0);
        }
        __syncthreads();
    }

#pragma unroll
    for (int j = 0; j < 4; ++j) {
        const int col = n0 + wn + j*16 + lr;
        const float bj = bias[col];
#pragma unroll
        for (int i = 0; i < 4; ++i) {
            const int row0 = m0 + wm + i*16 + lg*4;
#pragma unroll
            for (int rr = 0; rr < 4; ++rr) {
                float v = acc[i][j][rr] + bj;
                const size_t idx = (size_t)(row0 + rr) * N + col;
                if (MODE == 2) {
                    ((float*)Cout)[idx] = v + resid[idx];
                } else {
                    if (MODE == 1) v = 0.5f * v * (1.0f + erff(v * 0.70710678118654752f));
                    ((bf16*)Cout)[idx] = (bf16)v;
                }
            }
        }
    }
}

// ======================================================================
// Flash attention v2 (r11 exact). Grid (S/64, NQ, B), 256 thr.
// ======================================================================
__global__ __launch_bounds__(256) void attn_kernel(
    const bf16* __restrict__ qkv, const bf16* __restrict__ Vt,
    bf16* __restrict__ ctx)
{
    __shared__ bf16 lK[2][KVB*HD_];
    __shared__ bf16 lV[2][HD_*KVB];
    __shared__ bf16 lP[4][16*72];
    const int tid  = (int)threadIdx.x;
    const int wid  = tid >> 6;
    const int lane = tid & 63;
    const int lr   = lane & 15;
    const int lg   = lane >> 4;
    const int qt = (int)gridDim.x - 1 - (int)blockIdx.x;
    const int h = (int)blockIdx.y, b = (int)blockIdx.z;
    const int kh = h >> 2;
    const int qb = qt * 64;
    const int qw = qb + wid * 16;
    const float scale = 0.08838834764831845f;

    const bf16* kB[4];
    const bf16* vB[4];
#pragma unroll
    for (int i = 0; i < 4; ++i) {
        const int kRow = (wid*4 + i)*4 + (lane >> 4);
        const int kCol = ((lane & 15) ^ (kRow & 7)) * 8;
        kB[i] = qkv + (size_t)(b*S_ + kRow)*QKVN + H_ + kh*HD_ + kCol;
        const int vRow = (wid*4 + i)*8 + (lane >> 3);
        const int vCol = ((lane & 7) ^ (vRow & 7)) * 8;
        vB[i] = Vt + ((size_t)(b*NKV_ + kh)*HD_ + vRow)*S_ + vCol;
    }

    bf16x8 qf[4];
    {
        const bf16* qp = qkv + (size_t)(b*S_ + qw + lr)*QKVN + h*HD_ + lg*8;
#pragma unroll
        for (int t = 0; t < 4; ++t) qf[t] = *(const bf16x8*)(qp + t*32);
    }

    f32x4 o[8] = {};
    float mrow[4] = {-__builtin_inff(), -__builtin_inff(), -__builtin_inff(), -__builtin_inff()};
    float lrow[4] = {0.f, 0.f, 0.f, 0.f};
    const int nt = qt + 1;

#pragma unroll
    for (int i = 0; i < 4; ++i) {
        gload_lds16(kB[i], &lK[0][(wid*4 + i)*4*HD_]);
        gload_lds16(vB[i], &lV[0][(wid*4 + i)*8*KVB]);
    }

    int cur = 0;
    for (int t = 0; t < nt; ++t) {
        __syncthreads();
        if (t + 1 < nt) {
            const size_t kAdd = (size_t)(t+1)*KVB*QKVN;
            const size_t vAdd = (size_t)(t+1)*KVB;
#pragma unroll
            for (int i = 0; i < 4; ++i) {
                gload_lds16(kB[i] + kAdd, &lK[cur^1][(wid*4 + i)*4*HD_]);
                gload_lds16(vB[i] + vAdd, &lV[cur^1][(wid*4 + i)*8*KVB]);
            }
        }
        const int kv0 = t * KVB;

        f32x4 s[4] = {};
#pragma unroll
        for (int sub = 0; sub < 4; ++sub) {
            const int krow = sub*16 + lr;
            const bf16* kr = &lK[cur][krow*HD_];
            const int swk = (krow & 7) * 8;
#pragma unroll
            for (int d = 0; d < 4; ++d) {
                const bf16x8 kf = *(const bf16x8*)(kr + ((d*32 + lg*8) ^ swk));
                s[sub] = __builtin_amdgcn_mfma_f32_16x16x32_bf16(qf[d], kf, s[sub], 0, 0, 0);
            }
        }

        float p[4][4], rmax[4];
        if (t == qt) {
#pragma unroll
            for (int rr = 0; rr < 4; ++rr) {
                const int q = qw + lg*4 + rr;
                rmax[rr] = -__builtin_inff();
#pragma unroll
                for (int sub = 0; sub < 4; ++sub) {
                    const int kv = kv0 + sub*16 + lr;
                    const float v = s[sub][rr] * scale;
                    p[sub][rr] = (kv <= q) ? v : -__builtin_inff();
                    rmax[rr] = fmaxf(rmax[rr], p[sub][rr]);
                }
            }
        } else {
#pragma unroll
            for (int rr = 0; rr < 4; ++rr) {
                rmax[rr] = -__builtin_inff();
#pragma unroll
                for (int sub = 0; sub < 4; ++sub) {
                    p[sub][rr] = s[sub][rr] * scale;
                    rmax[rr] = fmaxf(rmax[rr], p[sub][rr]);
                }
            }
        }
#pragma unroll
        for (int d = 1; d < 16; d <<= 1)
#pragma unroll
            for (int rr = 0; rr < 4; ++rr)
                rmax[rr] = fmaxf(rmax[rr], __shfl_xor(rmax[rr], d));

        float fsc[4], rsum[4];
#pragma unroll
        for (int rr = 0; rr < 4; ++rr) {
            const float mn = fmaxf(mrow[rr], rmax[rr]);
            fsc[rr]  = __expf(mrow[rr] - mn);
            mrow[rr] = mn;
            rsum[rr] = 0.f;
#pragma unroll
            for (int sub = 0; sub < 4; ++sub) {
                p[sub][rr] = __expf(p[sub][rr] - mn);
                rsum[rr] += p[sub][rr];
            }
        }
#pragma unroll
        for (int d = 1; d < 16; d <<= 1)
#pragma unroll
            for (int rr = 0; rr < 4; ++rr)
                rsum[rr] += __shfl_xor(rsum[rr], d);
#pragma unroll
        for (int rr = 0; rr < 4; ++rr) lrow[rr] = lrow[rr]*fsc[rr] + rsum[rr];
#pragma unroll
        for (int dch = 0; dch < 8; ++dch)
#pragma unroll
            for (int rr = 0; rr < 4; ++rr) o[dch][rr] *= fsc[rr];

#pragma unroll
        for (int sub = 0; sub < 4; ++sub)
#pragma unroll
            for (int rr = 0; rr < 4; ++rr)
                lP[wid][(lg*4 + rr)*72 + sub*16 + lr] = (bf16)p[sub][rr];
        bf16x8 pfr[2];
#pragma unroll
        for (int kk = 0; kk < 2; ++kk)
            pfr[kk] = *(const bf16x8*)&lP[wid][lr*72 + kk*32 + lg*8];

#pragma unroll
        for (int dch = 0; dch < 8; ++dch) {
            const bf16* vr = &lV[cur][(dch*16 + lr)*KVB];
            const int swv = (lr & 7) * 8;
#pragma unroll
            for (int kk = 0; kk < 2; ++kk) {
                const bf16x8 vf = *(const bf16x8*)(vr + ((kk*32 + lg*8) ^ swv));
                o[dch] = __builtin_amdgcn_mfma_f32_16x16x32_bf16(pfr[kk], vf, o[dch], 0, 0, 0);
            }
        }
        cur ^= 1;
    }

#pragma unroll
    for (int rr = 0; rr < 4; ++rr) {
        const float inv = 1.0f / lrow[rr];
        bf16* cp = ctx + (size_t)(b*S_ + qw + lg*4 + rr) * H_ + h*HD_ + lr;
#pragma unroll
        for (int dch = 0; dch < 8; ++dch)
            cp[dch*16] = (bf16)(o[dch][rr] * inv);
    }
}

// ======================================================================
extern "C" void kernel_launch(void* const* d_in, const int* in_sizes, int n_in,
                              void* d_out, int out_size, void* d_ws, size_t ws_size,
                              hipStream_t stream)
{
    const float* hidden = (const float*)d_in[0];
    const float* Wq = (const float*)d_in[1];
    const float* bq = (const float*)d_in[2];
    const float* Wk = (const float*)d_in[3];
    const float* bk = (const float*)d_in[4];
    const float* Wv = (const float*)d_in[5];
    const float* bv = (const float*)d_in[6];
    const float* Wo = (const float*)d_in[7];
    const float* bo = (const float*)d_in[8];
    const float* W1 = (const float*)d_in[9];
    const float* b1 = (const float*)d_in[10];
    const float* W2 = (const float*)d_in[11];
    const float* b2 = (const float*)d_in[12];
    const float* g1 = (const float*)d_in[13];
    const float* g2 = (const float*)d_in[14];
    float* out = (float*)d_out;

    // d_ws is 256 MiB; vt aliases xn1 (dead after QKV GEMM).
    // Footprint = 264,253,440 B (proven fit).
    char* p = (char*)d_ws;
    auto alloc = [&](size_t bytes) { char* r = p; p += (bytes + 255) & ~(size_t)255; return r; };
    bf16*  wt_qkv = (bf16*)alloc((size_t)QKVN * H_ * 2);
    bf16*  wo_t   = (bf16*)alloc((size_t)H_ * H_ * 2);
    bf16*  w1_t   = (bf16*)alloc((size_t)FF_ * H_ * 2);
    bf16*  w2_t   = (bf16*)alloc((size_t)H_ * FF_ * 2);
    float* bqkv   = (float*)alloc((size_t)QKVN * 4);
    bf16*  xn1    = (bf16*)alloc((size_t)TOK * H_ * 2);
    bf16*  qkv    = (bf16*)alloc((size_t)TOK * QKVN * 2);
    bf16*  ctxb   = (bf16*)alloc((size_t)TOK * H_ * 2);
    float* x1     = (float*)alloc((size_t)TOK * H_ * 4);
    bf16*  xn2    = (bf16*)alloc((size_t)TOK * H_ * 2);
    bf16*  ffn    = (bf16*)alloc((size_t)TOK * FF_ * 2);
    bf16*  vt     = xn1;    // alias (xn1 dead after QKV GEMM)

    const dim3 blk(256);
    biaspack_kernel<<<dim3(QKVN/256), blk, 0, stream>>>(bq, bk, bv, bqkv);
    wtrans_kernel<<<dim3(H_/32,  H_/32),  blk, 0, stream>>>(Wq, wt_qkv, H_, H_,  0);
    wtrans_kernel<<<dim3(512/32, H_/32),  blk, 0, stream>>>(Wk, wt_qkv, H_, 512, H_);
    wtrans_kernel<<<dim3(512/32, H_/32),  blk, 0, stream>>>(Wv, wt_qkv, H_, 512, H_ + 512);
    wtrans_kernel<<<dim3(H_/32,  H_/32),  blk, 0, stream>>>(Wo, wo_t,   H_, H_,  0);
    wtrans_kernel<<<dim3(FF_/32, H_/32),  blk, 0, stream>>>(W1, w1_t,   H_, FF_, 0);
    wtrans_kernel<<<dim3(H_/32,  FF_/32), blk, 0, stream>>>(W2, w2_t,   FF_, H_, 0);

    rmsnorm_kernel<<<dim3(TOK), blk, 0, stream>>>(hidden, g1, xn1);
    // QKV (control, swizzled): grid 24x32 = 768 wg
    gemm_kernel<0><<<dim3(QKVN/128, TOK/128), blk, 0, stream>>>(
        xn1, wt_qkv, bqkv, nullptr, qkv, TOK, QKVN, H_);
    vtrans_kernel<<<dim3(TOK/32, HD_/32, NKV_), blk, 0, stream>>>(qkv, vt);
    // attention v2: grid (32, 16, 2) = 1024 blocks
    attn_kernel<<<dim3(S_/64, NQ_, B_), blk, 0, stream>>>(qkv, vt, ctxb);
    // O-proj (control, swizzled): +resid(hidden) -> x1 f32
    gemm_kernel<2><<<dim3(H_/128, TOK/128), blk, 0, stream>>>(
        ctxb, wo_t, bo, hidden, x1, TOK, H_, H_);
    rmsnorm_kernel<<<dim3(TOK), blk, 0, stream>>>(x1, g2, xn2);
    // FFN1 EXPERIMENT (no-swizzle, m97-exact LDS path): GELU -> ffn
    gemm_nosw_kernel<1><<<dim3(FF_/128, TOK/128), blk, 0, stream>>>(
        xn2, w1_t, b1, nullptr, ffn, TOK, FF_, H_);
    // FFN2 (control, swizzled): direct, +resid(x1) -> out f32
    gemm_kernel<2><<<dim3(H_/128, TOK/128), blk, 0, stream>>>(
        ffn, w2_t, b2, x1, out, TOK, H_, FF_);
}

// Round 17
// 728.810 us; speedup vs baseline: 1.0529x; 1.0529x over previous
//
#include <hip/hip_runtime.h>
#include <cstdint>

// ---- problem constants ----
#define H_    2048
#define NQ_   16
#define NKV_  4
#define HD_   128
#define FF_   8192
#define B_    2
#define S_    2048
#define TOK   (B_*S_)            // 4096 tokens
#define QKVN  (H_ + 2*NKV_*HD_)  // 3072 = Q(2048) | K(512) | V(512)
#define KVB   64                 // attention KV tile

typedef __bf16 bf16;
typedef bf16  bf16x8 __attribute__((ext_vector_type(8)));
typedef float f32x4  __attribute__((ext_vector_type(4)));

typedef __attribute__((address_space(1))) void as1_void;
typedef __attribute__((address_space(3))) void as3_void;

__device__ __forceinline__ void gload_lds16(const void* g, void* l) {
    __builtin_amdgcn_global_load_lds((as1_void*)g, (as3_void*)l, 16, 0, 0);
}

// ======================================================================
// Weight convert + transpose: W[K][N] f32 -> Wt[outOff+N][K] bf16
// ======================================================================
__global__ __launch_bounds__(256) void wtrans_kernel(
    const float* __restrict__ W, bf16* __restrict__ Wt, int K, int N, int outOff)
{
    __shared__ float tile[32][33];
    const int n0 = (int)blockIdx.x * 32;
    const int k0 = (int)blockIdx.y * 32;
    const int c  = (int)threadIdx.x & 31;
    const int r  = (int)threadIdx.x >> 5;
#pragma unroll
    for (int i = 0; i < 4; ++i)
        tile[r + i*8][c] = W[(size_t)(k0 + r + i*8) * N + n0 + c];
    __syncthreads();
#pragma unroll
    for (int i = 0; i < 4; ++i)
        Wt[(size_t)(outOff + n0 + r + i*8) * K + k0 + c] = (bf16)tile[c][r + i*8];
}

__global__ void biaspack_kernel(const float* __restrict__ bq, const float* __restrict__ bk,
                                const float* __restrict__ bv, float* __restrict__ out)
{
    const int i = (int)(blockIdx.x * 256 + threadIdx.x);
    out[i] = (i < H_) ? bq[i] : (i < H_ + NKV_*HD_ ? bk[i - H_] : bv[i - H_ - NKV_*HD_]);
}

// ======================================================================
// RMSNorm: x f32 [rows][2048] -> y bf16
// ======================================================================
__global__ __launch_bounds__(256) void rmsnorm_kernel(
    const float* __restrict__ x, const float* __restrict__ g, bf16* __restrict__ y)
{
    const int row = (int)blockIdx.x;
    const int tid = (int)threadIdx.x;
    const float* xr = x + (size_t)row * H_;
    const float4 a = *(const float4*)(xr + tid*8);
    const float4 c = *(const float4*)(xr + tid*8 + 4);
    float ss = a.x*a.x + a.y*a.y + a.z*a.z + a.w*a.w
             + c.x*c.x + c.y*c.y + c.z*c.z + c.w*c.w;
#pragma unroll
    for (int d = 1; d < 64; d <<= 1) ss += __shfl_xor(ss, d);
    __shared__ float red[4];
    if ((tid & 63) == 0) red[tid >> 6] = ss;
    __syncthreads();
    const float inv = rsqrtf((red[0]+red[1]+red[2]+red[3]) * (1.0f/H_) + 1e-6f);
    const float vals[8] = {a.x,a.y,a.z,a.w,c.x,c.y,c.z,c.w};
    const float* gp = g + tid*8;
    bf16x8 outv;
#pragma unroll
    for (int e = 0; e < 8; ++e) outv[e] = (bf16)(vals[e] * inv * gp[e]);
    *(bf16x8*)(y + (size_t)row * H_ + tid*8) = outv;
}

// ======================================================================
// V transpose: qkv[tok][3072] V-slice -> Vt[(b*NKV+kh)*HD + d][S]
// ======================================================================
__global__ __launch_bounds__(256) void vtrans_kernel(
    const bf16* __restrict__ qkv, bf16* __restrict__ Vt)
{
    __shared__ bf16 tile[32][33];
    const int tt = (int)blockIdx.x;
    const int d0 = (int)blockIdx.y * 32;
    const int kh = (int)blockIdx.z;
    const int b  = (tt*32) / S_;
    const int s0 = (tt*32) % S_;
    const int c = (int)threadIdx.x & 31;
    const int r = (int)threadIdx.x >> 5;
#pragma unroll
    for (int i = 0; i < 4; ++i)
        tile[r + i*8][c] = qkv[(size_t)(tt*32 + r + i*8)*QKVN + H_ + NKV_*HD_ + kh*HD_ + d0 + c];
    __syncthreads();
#pragma unroll
    for (int i = 0; i < 4; ++i)
        Vt[((size_t)(b*NKV_ + kh)*HD_ + d0 + r + i*8)*S_ + s0 + c] = tile[c][r + i*8];
}

// ======================================================================
// GEMM (r15 exact — the verified optimum of 12 measured variants):
// 2-barrier 128x128, XCD-chunk + 8m x 4n superblock, swizzled LDS
// (r16 A/B confirmed swizzle is +11% vs linear), launch_bounds(256,3).
// MODE 0: +bias -> bf16. 1: GELU(v+bias) -> bf16. 2: v+bias+resid -> f32.
// ======================================================================
template<int MODE>
__global__ __launch_bounds__(256, 3) void gemm_kernel(
    const bf16* __restrict__ A, const bf16* __restrict__ Bt,
    const float* __restrict__ bias, const float* __restrict__ resid,
    void* __restrict__ Cout, int M, int N, int K)
{
    __shared__ bf16 lA[128*64];
    __shared__ bf16 lB[128*64];
    const int tid  = (int)threadIdx.x;
    const int wid  = tid >> 6;
    const int lane = tid & 63;
    const int lr   = lane & 15;
    const int lg   = lane >> 4;

    const int gx  = (int)gridDim.x;
    const int nwg = gx * (int)gridDim.y;
    int wg = (int)blockIdx.y * gx + (int)blockIdx.x;
    wg = (wg & 7) * (nwg >> 3) + (wg >> 3);
    const int nsup  = gx >> 2;
    const int chunk = wg >> 5;
    const int cin   = wg & 31;
    const int m0 = ((chunk / nsup) * 8 + (cin >> 2)) * 128;
    const int n0 = ((chunk % nsup) * 4 + (cin & 3)) * 128;

    const int wm = (wid >> 1) * 64;
    const int wn = (wid & 1) * 64;

    f32x4 acc[4][4] = {};

    const int sRow = wid*32 + (lane >> 3);
    const int sCol = ((lane & 7) ^ (lane >> 3)) * 8;
    const bf16* aSrc = A  + (size_t)(m0 + sRow) * K + sCol;
    const bf16* bSrc = Bt + (size_t)(n0 + sRow) * K + sCol;

    for (int k0 = 0; k0 < K; k0 += 64) {
#pragma unroll
        for (int i = 0; i < 4; ++i) {
            gload_lds16(aSrc + (size_t)(i*8)*K + k0, &lA[(wid*32 + i*8)*64]);
            gload_lds16(bSrc + (size_t)(i*8)*K + k0, &lB[(wid*32 + i*8)*64]);
        }
        __syncthreads();
#pragma unroll
        for (int kk = 0; kk < 64; kk += 32) {
            const int ks = (kk + lg*8) ^ ((lr & 7) * 8);
            bf16x8 af[4], bfr[4];
#pragma unroll
            for (int i = 0; i < 4; ++i)
                af[i] = *(const bf16x8*)&lA[(wm + i*16 + lr)*64 + ks];
#pragma unroll
            for (int j = 0; j < 4; ++j)
                bfr[j] = *(const bf16x8*)&lB[(wn + j*16 + lr)*64 + ks];
#pragma unroll
            for (int i = 0; i < 4; ++i)
#pragma unroll
                for (int j = 0; j < 4; ++j)
                    acc[i][j] = __builtin_amdgcn_mfma_f32_16x16x32_bf16(
                        af[i], bfr[j], acc[i][j], 0, 0, 0);
        }
        __syncthreads();
    }

#pragma unroll
    for (int j = 0; j < 4; ++j) {
        const int col = n0 + wn + j*16 + lr;
        const float bj = bias[col];
#pragma unroll
        for (int i = 0; i < 4; ++i) {
            const int row0 = m0 + wm + i*16 + lg*4;
#pragma unroll
            for (int rr = 0; rr < 4; ++rr) {
                float v = acc[i][j][rr] + bj;
                const size_t idx = (size_t)(row0 + rr) * N + col;
                if (MODE == 2) {
                    ((float*)Cout)[idx] = v + resid[idx];
                } else {
                    if (MODE == 1) v = 0.5f * v * (1.0f + erff(v * 0.70710678118654752f));
                    ((bf16*)Cout)[idx] = (bf16)v;
                }
            }
        }
    }
}

// ======================================================================
// Flash attention v2 (r11/r15 exact). Grid (S/64, NQ, B), 256 thr.
// ======================================================================
__global__ __launch_bounds__(256) void attn_kernel(
    const bf16* __restrict__ qkv, const bf16* __restrict__ Vt,
    bf16* __restrict__ ctx)
{
    __shared__ bf16 lK[2][KVB*HD_];
    __shared__ bf16 lV[2][HD_*KVB];
    __shared__ bf16 lP[4][16*72];
    const int tid  = (int)threadIdx.x;
    const int wid  = tid >> 6;
    const int lane = tid & 63;
    const int lr   = lane & 15;
    const int lg   = lane >> 4;
    const int qt = (int)gridDim.x - 1 - (int)blockIdx.x;
    const int h = (int)blockIdx.y, b = (int)blockIdx.z;
    const int kh = h >> 2;
    const int qb = qt * 64;
    const int qw = qb + wid * 16;
    const float scale = 0.08838834764831845f;

    const bf16* kB[4];
    const bf16* vB[4];
#pragma unroll
    for (int i = 0; i < 4; ++i) {
        const int kRow = (wid*4 + i)*4 + (lane >> 4);
        const int kCol = ((lane & 15) ^ (kRow & 7)) * 8;
        kB[i] = qkv + (size_t)(b*S_ + kRow)*QKVN + H_ + kh*HD_ + kCol;
        const int vRow = (wid*4 + i)*8 + (lane >> 3);
        const int vCol = ((lane & 7) ^ (vRow & 7)) * 8;
        vB[i] = Vt + ((size_t)(b*NKV_ + kh)*HD_ + vRow)*S_ + vCol;
    }

    bf16x8 qf[4];
    {
        const bf16* qp = qkv + (size_t)(b*S_ + qw + lr)*QKVN + h*HD_ + lg*8;
#pragma unroll
        for (int t = 0; t < 4; ++t) qf[t] = *(const bf16x8*)(qp + t*32);
    }

    f32x4 o[8] = {};
    float mrow[4] = {-__builtin_inff(), -__builtin_inff(), -__builtin_inff(), -__builtin_inff()};
    float lrow[4] = {0.f, 0.f, 0.f, 0.f};
    const int nt = qt + 1;

#pragma unroll
    for (int i = 0; i < 4; ++i) {
        gload_lds16(kB[i], &lK[0][(wid*4 + i)*4*HD_]);
        gload_lds16(vB[i], &lV[0][(wid*4 + i)*8*KVB]);
    }

    int cur = 0;
    for (int t = 0; t < nt; ++t) {
        __syncthreads();
        if (t + 1 < nt) {
            const size_t kAdd = (size_t)(t+1)*KVB*QKVN;
            const size_t vAdd = (size_t)(t+1)*KVB;
#pragma unroll
            for (int i = 0; i < 4; ++i) {
                gload_lds16(kB[i] + kAdd, &lK[cur^1][(wid*4 + i)*4*HD_]);
                gload_lds16(vB[i] + vAdd, &lV[cur^1][(wid*4 + i)*8*KVB]);
            }
        }
        const int kv0 = t * KVB;

        f32x4 s[4] = {};
#pragma unroll
        for (int sub = 0; sub < 4; ++sub) {
            const int krow = sub*16 + lr;
            const bf16* kr = &lK[cur][krow*HD_];
            const int swk = (krow & 7) * 8;
#pragma unroll
            for (int d = 0; d < 4; ++d) {
                const bf16x8 kf = *(const bf16x8*)(kr + ((d*32 + lg*8) ^ swk));
                s[sub] = __builtin_amdgcn_mfma_f32_16x16x32_bf16(qf[d], kf, s[sub], 0, 0, 0);
            }
        }

        float p[4][4], rmax[4];
        if (t == qt) {
#pragma unroll
            for (int rr = 0; rr < 4; ++rr) {
                const int q = qw + lg*4 + rr;
                rmax[rr] = -__builtin_inff();
#pragma unroll
                for (int sub = 0; sub < 4; ++sub) {
                    const int kv = kv0 + sub*16 + lr;
                    const float v = s[sub][rr] * scale;
                    p[sub][rr] = (kv <= q) ? v : -__builtin_inff();
                    rmax[rr] = fmaxf(rmax[rr], p[sub][rr]);
                }
            }
        } else {
#pragma unroll
            for (int rr = 0; rr < 4; ++rr) {
                rmax[rr] = -__builtin_inff();
#pragma unroll
                for (int sub = 0; sub < 4; ++sub) {
                    p[sub][rr] = s[sub][rr] * scale;
                    rmax[rr] = fmaxf(rmax[rr], p[sub][rr]);
                }
            }
        }
#pragma unroll
        for (int d = 1; d < 16; d <<= 1)
#pragma unroll
            for (int rr = 0; rr < 4; ++rr)
                rmax[rr] = fmaxf(rmax[rr], __shfl_xor(rmax[rr], d));

        float fsc[4], rsum[4];
#pragma unroll
        for (int rr = 0; rr < 4; ++rr) {
            const float mn = fmaxf(mrow[rr], rmax[rr]);
            fsc[rr]  = __expf(mrow[rr] - mn);
            mrow[rr] = mn;
            rsum[rr] = 0.f;
#pragma unroll
            for (int sub = 0; sub < 4; ++sub) {
                p[sub][rr] = __expf(p[sub][rr] - mn);
                rsum[rr] += p[sub][rr];
            }
        }
#pragma unroll
        for (int d = 1; d < 16; d <<= 1)
#pragma unroll
            for (int rr = 0; rr < 4; ++rr)
                rsum[rr] += __shfl_xor(rsum[rr], d);
#pragma unroll
        for (int rr = 0; rr < 4; ++rr) lrow[rr] = lrow[rr]*fsc[rr] + rsum[rr];
#pragma unroll
        for (int dch = 0; dch < 8; ++dch)
#pragma unroll
            for (int rr = 0; rr < 4; ++rr) o[dch][rr] *= fsc[rr];

#pragma unroll
        for (int sub = 0; sub < 4; ++sub)
#pragma unroll
            for (int rr = 0; rr < 4; ++rr)
                lP[wid][(lg*4 + rr)*72 + sub*16 + lr] = (bf16)p[sub][rr];
        bf16x8 pfr[2];
#pragma unroll
        for (int kk = 0; kk < 2; ++kk)
            pfr[kk] = *(const bf16x8*)&lP[wid][lr*72 + kk*32 + lg*8];

#pragma unroll
        for (int dch = 0; dch < 8; ++dch) {
            const bf16* vr = &lV[cur][(dch*16 + lr)*KVB];
            const int swv = (lr & 7) * 8;
#pragma unroll
            for (int kk = 0; kk < 2; ++kk) {
                const bf16x8 vf = *(const bf16x8*)(vr + ((kk*32 + lg*8) ^ swv));
                o[dch] = __builtin_amdgcn_mfma_f32_16x16x32_bf16(pfr[kk], vf, o[dch], 0, 0, 0);
            }
        }
        cur ^= 1;
    }

#pragma unroll
    for (int rr = 0; rr < 4; ++rr) {
        const float inv = 1.0f / lrow[rr];
        bf16* cp = ctx + (size_t)(b*S_ + qw + lg*4 + rr) * H_ + h*HD_ + lr;
#pragma unroll
        for (int dch = 0; dch < 8; ++dch)
            cp[dch*16] = (bf16)(o[dch][rr] * inv);
    }
}

// ======================================================================
extern "C" void kernel_launch(void* const* d_in, const int* in_sizes, int n_in,
                              void* d_out, int out_size, void* d_ws, size_t ws_size,
                              hipStream_t stream)
{
    const float* hidden = (const float*)d_in[0];
    const float* Wq = (const float*)d_in[1];
    const float* bq = (const float*)d_in[2];
    const float* Wk = (const float*)d_in[3];
    const float* bk = (const float*)d_in[4];
    const float* Wv = (const float*)d_in[5];
    const float* bv = (const float*)d_in[6];
    const float* Wo = (const float*)d_in[7];
    const float* bo = (const float*)d_in[8];
    const float* W1 = (const float*)d_in[9];
    const float* b1 = (const float*)d_in[10];
    const float* W2 = (const float*)d_in[11];
    const float* b2 = (const float*)d_in[12];
    const float* g1 = (const float*)d_in[13];
    const float* g2 = (const float*)d_in[14];
    float* out = (float*)d_out;

    // d_ws is 256 MiB; vt aliases xn1 (dead after QKV GEMM).
    // Footprint = 264,253,440 B (proven fit).
    char* p = (char*)d_ws;
    auto alloc = [&](size_t bytes) { char* r = p; p += (bytes + 255) & ~(size_t)255; return r; };
    bf16*  wt_qkv = (bf16*)alloc((size_t)QKVN * H_ * 2);
    bf16*  wo_t   = (bf16*)alloc((size_t)H_ * H_ * 2);
    bf16*  w1_t   = (bf16*)alloc((size_t)FF_ * H_ * 2);
    bf16*  w2_t   = (bf16*)alloc((size_t)H_ * FF_ * 2);
    float* bqkv   = (float*)alloc((size_t)QKVN * 4);
    bf16*  xn1    = (bf16*)alloc((size_t)TOK * H_ * 2);
    bf16*  qkv    = (bf16*)alloc((size_t)TOK * QKVN * 2);
    bf16*  ctxb   = (bf16*)alloc((size_t)TOK * H_ * 2);
    float* x1     = (float*)alloc((size_t)TOK * H_ * 4);
    bf16*  xn2    = (bf16*)alloc((size_t)TOK * H_ * 2);
    bf16*  ffn    = (bf16*)alloc((size_t)TOK * FF_ * 2);
    bf16*  vt     = xn1;    // alias (xn1 dead after QKV GEMM)

    const dim3 blk(256);
    biaspack_kernel<<<dim3(QKVN/256), blk, 0, stream>>>(bq, bk, bv, bqkv);
    wtrans_kernel<<<dim3(H_/32,  H_/32),  blk, 0, stream>>>(Wq, wt_qkv, H_, H_,  0);
    wtrans_kernel<<<dim3(512/32, H_/32),  blk, 0, stream>>>(Wk, wt_qkv, H_, 512, H_);
    wtrans_kernel<<<dim3(512/32, H_/32),  blk, 0, stream>>>(Wv, wt_qkv, H_, 512, H_ + 512);
    wtrans_kernel<<<dim3(H_/32,  H_/32),  blk, 0, stream>>>(Wo, wo_t,   H_, H_,  0);
    wtrans_kernel<<<dim3(FF_/32, H_/32),  blk, 0, stream>>>(W1, w1_t,   H_, FF_, 0);
    wtrans_kernel<<<dim3(H_/32,  FF_/32), blk, 0, stream>>>(W2, w2_t,   FF_, H_, 0);

    rmsnorm_kernel<<<dim3(TOK), blk, 0, stream>>>(hidden, g1, xn1);
    // QKV: grid 24x32 = 768 wg
    gemm_kernel<0><<<dim3(QKVN/128, TOK/128), blk, 0, stream>>>(
        xn1, wt_qkv, bqkv, nullptr, qkv, TOK, QKVN, H_);
    vtrans_kernel<<<dim3(TOK/32, HD_/32, NKV_), blk, 0, stream>>>(qkv, vt);
    // attention v2: grid (32, 16, 2) = 1024 blocks
    attn_kernel<<<dim3(S_/64, NQ_, B_), blk, 0, stream>>>(qkv, vt, ctxb);
    // O-proj: +resid(hidden) -> x1 f32 ; grid 16x32 = 512 wg
    gemm_kernel<2><<<dim3(H_/128, TOK/128), blk, 0, stream>>>(
        ctxb, wo_t, bo, hidden, x1, TOK, H_, H_);
    rmsnorm_kernel<<<dim3(TOK), blk, 0, stream>>>(x1, g2, xn2);
    // FFN1: GELU -> ffn ; grid 64x32 = 2048 wg
    gemm_kernel<1><<<dim3(FF_/128, TOK/128), blk, 0, stream>>>(
        xn2, w1_t, b1, nullptr, ffn, TOK, FF_, H_);
    // FFN2: direct, +resid(x1) -> out f32 ; grid 16x32 = 512 wg
    gemm_kernel<2><<<dim3(H_/128, TOK/128), blk, 0, stream>>>(
        ffn, w2_t, b2, x1, out, TOK, H_, FF_);
}